// Round 8
// baseline (183.672 us; speedup 1.0000x reference)
//
#include <hip/hip_runtime.h>
#include <hip/hip_bf16.h>
#include <math.h>

// ---------------------------------------------------------------------------
// LowRankSparseAttention on MI355X (gfx950)
//   1. prep: cvt resid->A_bf, cvt W_V->Wt rows 2048+, virtual K/V fills,
//      transpose W_Q/W_K->Wt, transpose W_O->Wot
//   2. gemm1_fused (128x128): QKV proj, fused epilogue:
//        QK tiles use SWAPPED mfma operands (D = W x resid^T) so each lane
//        owns 4 consecutive dims x 4 tokens -> rotary in-lane, short4 stores:
//        Q: +bQ, rotary, /sqrt(32) -> Qb bf16 [(b,h)][1024][32]
//        K: +bK, rotary            -> Kb bf16 [(b,h)][1152][32]
//        V: +bV -> Vb bf16 [(b,h)][17 chunks][8KB], token-permuted within
//           32-groups AND XOR-swizzled 16B units: slot = ch*8 + (q ^ (ch&7))
//   3. attn_mfma: per-wave flash attn (S^T/O^T, P in regs); V chunk staged
//      to LDS via contiguous global_load_lds, software-pipelined -> Zb bf16
//   4. gemm2 (128x64 tiles, 256 blocks, XCD-swizzled): out = Zb @ Wot^T
// ---------------------------------------------------------------------------

typedef short bf16x8 __attribute__((ext_vector_type(8)));
typedef short short4v __attribute__((ext_vector_type(4)));
typedef float f32x4 __attribute__((ext_vector_type(4)));
typedef int int4v __attribute__((ext_vector_type(4)));
typedef __hip_bfloat16 bf16;

#define AS1(p) ((const __attribute__((address_space(1))) void*)(const void*)(p))
#define AS3(p) ((__attribute__((address_space(3))) void*)(void*)(p))

static constexpr float INV_SCALE = 0.17677669529663687f;  // 1/sqrt(32)

// fast RNE f32->bf16 (finite values only): 4 int ops
__device__ inline short rnd_bf16(float x) {
  unsigned u = __float_as_uint(x);
  return (short)((u + 0x7fffu + ((u >> 16) & 1u)) >> 16);
}

// pack two positive f32 -> dword of bf16 pair (round half-up)
__device__ inline int pack_bf16_pair(float hi, float lo) {
  unsigned a = __float_as_uint(hi) + 0x8000u;
  unsigned b = __float_as_uint(lo) + 0x8000u;
  return (int)__builtin_amdgcn_perm(a, b, 0x07060302u);
}

// ---- merged preprocessing kernel ------------------------------------------
__global__ __launch_bounds__(256) void prep(
    const float* __restrict__ resid, const float* __restrict__ WV,
    const float* __restrict__ WQ, const float* __restrict__ WK,
    const float* __restrict__ WO, const float* __restrict__ vk,
    const float* __restrict__ vv,
    bf16* __restrict__ A_bf, bf16* __restrict__ Wt, bf16* __restrict__ Wot,
    bf16* __restrict__ Kb, bf16* __restrict__ Vb) {
  __shared__ float t[64][65];
  const int blk = blockIdx.x, tid = threadIdx.x;
  if (blk < 4096) {
    const float* src = (blk < 2048) ? resid : WV;
    short* dst = (short*)((blk < 2048) ? A_bf : (Wt + (size_t)2048 * 1024));
    int i = ((blk & 2047) * 256 + tid) * 4;
    float4 v = *(const float4*)(src + i);
    dst[i + 0] = rnd_bf16(v.x); dst[i + 1] = rnd_bf16(v.y);
    dst[i + 2] = rnd_bf16(v.z); dst[i + 3] = rnd_bf16(v.w);
  } else if (blk < 7168) {
    int idx = (blk - 4096) * 256 + tid;
    if (idx < 262144) {              // Kb virtual: toks 1024..1151 per (b,h)
      int b = idx >> 17, rem = idx & 131071;
      int j = rem >> 10, c = rem & 1023;     // c = h*32+d
      int h = c >> 5, d = c & 31;
      float v = (j < 16) ? vk[j * 1024 + c] : 0.f;
      Kb[(((size_t)(b * 32 + h)) * 1152 + 1024 + j) * 32 + d] = __float2bfloat16(v);
    } else if (idx < 524288) {       // Vb virtual: chunk 16 (toks 1024..1087)
      int i2 = idx - 262144;         // [0, 262144): 2 b x 2048 ch x 64 p
      int b = i2 >> 17, rem = i2 & 131071;
      int ch = rem >> 6, p = rem & 63;
      int pl = p & 31;
      int u = (p & 32) | ((pl & 4) << 2) | ((pl & 24) >> 1) | (pl & 3);
      float v = (u < 16) ? vv[(size_t)u * 2048 + ch] : 0.f;
      int hv = ch >> 6, c = ch & 63;
      int slot = c * 8 + ((p >> 3) ^ (c & 7));
      Vb[((((size_t)(b * 32 + hv)) * 17 + 16) * 512 + slot) * 8 + (p & 7)] = __float2bfloat16(v);
    }
  } else if (blk < 8192) {
    int i = blk - 7168;
    int mt = i & 15, h = (i >> 4) & 31, qk = i >> 9;
    const float* W = qk ? WK : WQ;
    const int m0 = mt * 64;
    for (int idx = tid; idx < 64 * 32; idx += 256) {
      int ii = idx >> 5, d = idx & 31;
      t[ii][d] = W[((size_t)h * 1024 + m0 + ii) * 32 + d];
    }
    __syncthreads();
    const int rowbase = qk * 1024 + h * 32;
    for (int idx = tid; idx < 32 * 64; idx += 256) {
      int d = idx >> 6, ii = idx & 63;
      Wt[(size_t)(rowbase + d) * 1024 + m0 + ii] = __float2bfloat16(t[ii][d]);
    }
  } else {
    int i = blk - 8192;
    int h0 = (i & 31) * 64, m0 = (i >> 5) * 64;
    for (int idx = tid; idx < 64 * 64; idx += 256) {
      int ii = idx >> 6, j = idx & 63;
      t[ii][j] = WO[(size_t)(h0 + ii) * 1024 + m0 + j];
    }
    __syncthreads();
    for (int idx = tid; idx < 64 * 64; idx += 256) {
      int ii = idx >> 6, j = idx & 63;
      Wot[(size_t)(m0 + ii) * 2048 + h0 + j] = __float2bfloat16(t[j][ii]);
    }
  }
}

// ---- GEMM1 + fused epilogue: 128(tok) x 128(feat) tiles, K=1024 -----------
// QK tiles: acc[fj][ti] = mfma(W-frag, resid-frag) -> D[m=feature][n=token].
//   Lane owns features quad*4..+3 (+16 via fj parity) x tokens {ti x col}:
//   rotary pair in-lane, bias via float4, stores are short4 (coalesced).
// V tiles: original order -> D[m=token][n=channel], permuted+swizzled store.
__global__ __launch_bounds__(256) void gemm1_fused(
    const bf16* __restrict__ A, const bf16* __restrict__ Bt,
    const float* __restrict__ bQ, const float* __restrict__ bK,
    const float* __restrict__ bV,
    bf16* __restrict__ Qb, bf16* __restrict__ Kb, bf16* __restrict__ Vb) {
  __shared__ __align__(16) short As[128 * 32];
  __shared__ __align__(16) short Bs[128 * 32];
  // XCD swizzle: xcd owns 2 token-bands x all feature tiles
  const int flat = blockIdx.x;
  const int xcd = flat & 7, idx = flat >> 3;          // idx 0..63
  const int tileM = (xcd * 2 + (idx >> 5)) * 128;     // token band
  const int tileN = (idx & 31) * 128;                 // feature tile
  const int tid = threadIdx.x, wave = tid >> 6, lane = tid & 63;
  const int wm = (wave >> 1) * 64, wn = (wave & 1) * 64;
  const int mrow = lane & 15, kq = lane >> 4;
  const bool isQK = tileN < 2048;
  f32x4 acc[4][4] = {};

  for (int k0 = 0; k0 < 1024; k0 += 32) {
#pragma unroll
    for (int i = 0; i < 2; i++) {
      int c = (wave * 2 + i) * 64 + lane;
      int row = c >> 2, ko = (c & 3) * 8;
      const short* ga = (const short*)A + (size_t)(tileM + row) * 1024 + k0 + ko;
      const short* gb = (const short*)Bt + (size_t)(tileN + row) * 1024 + k0 + ko;
      __builtin_amdgcn_global_load_lds(AS1(ga), AS3(&As[(wave * 2 + i) * 512]), 16, 0, 0);
      __builtin_amdgcn_global_load_lds(AS1(gb), AS3(&Bs[(wave * 2 + i) * 512]), 16, 0, 0);
    }
    __syncthreads();
    bf16x8 af[4], bfr[4];
#pragma unroll
    for (int t = 0; t < 4; t++) {
      af[t]  = *(const bf16x8*)&As[(wm + t * 16 + mrow) * 32 + kq * 8];
      bfr[t] = *(const bf16x8*)&Bs[(wn + t * 16 + mrow) * 32 + kq * 8];
    }
    if (isQK) {
#pragma unroll
      for (int fj = 0; fj < 4; fj++)
#pragma unroll
        for (int ti = 0; ti < 4; ti++)
          acc[fj][ti] = __builtin_amdgcn_mfma_f32_16x16x32_bf16(bfr[fj], af[ti], acc[fj][ti], 0, 0, 0);
    } else {
#pragma unroll
      for (int i = 0; i < 4; i++)
#pragma unroll
        for (int j = 0; j < 4; j++)
          acc[i][j] = __builtin_amdgcn_mfma_f32_16x16x32_bf16(af[i], bfr[j], acc[i][j], 0, 0, 0);
    }
    __syncthreads();
  }

  const int col = lane & 15, rq = lane >> 4;
  if (isQK) {
    // ---- two QK heads/wave: D[m=feature][n=token]; d0 = rq*4 -------------
    const int qk = tileN >> 10;
    const float* bias = qk ? bK : bQ;
    const int hA = ((tileN & 1023) + wn) >> 5;
    const int d0 = rq * 4;
    const float4 bA0 = *(const float4*)&bias[hA * 32 + d0];
    const float4 bA1 = *(const float4*)&bias[hA * 32 + 16 + d0];
    const float4 bB0 = *(const float4*)&bias[(hA + 1) * 32 + d0];
    const float4 bB1 = *(const float4*)&bias[(hA + 1) * 32 + 16 + d0];
    float invf[4];
#pragma unroll
    for (int r = 0; r < 4; r++)
      invf[r] = exp2f((d0 + r) * -0.8304820237218406f);  // -log2(10000)/16
    const float osc = qk ? 1.f : INV_SCALE;
#pragma unroll
    for (int ti = 0; ti < 4; ti++) {
      int sg = tileM + wm + ti * 16 + col;
      int s = sg & 1023, bb = sg >> 10;
      float sv[4], cv[4];
#pragma unroll
      for (int r = 0; r < 4; r++) __sincosf((float)s * invf[r], &sv[r], &cv[r]);
#pragma unroll
      for (int p = 0; p < 2; p++) {
        int h = hA + p;
        short4v z0, z1;
#pragma unroll
        for (int r = 0; r < 4; r++) {
          float x0 = acc[2 * p][ti][r]     + (p ? (&bB0.x)[r] : (&bA0.x)[r]);
          float x1 = acc[2 * p + 1][ti][r] + (p ? (&bB1.x)[r] : (&bA1.x)[r]);
          float y0 = (x0 * cv[r] - x1 * sv[r]) * osc;
          float y1 = (x1 * cv[r] + x0 * sv[r]) * osc;
          z0[r] = rnd_bf16(y0); z1[r] = rnd_bf16(y1);
        }
        short* dst = qk
            ? (short*)Kb + ((size_t)(bb * 32 + h) * 1152 + s) * 32
            : (short*)Qb + ((size_t)(bb * 32 + h) * 1024 + s) * 32;
        *(short4v*)(dst + d0) = z0;
        *(short4v*)(dst + 16 + d0) = z1;
      }
    }
  } else {
    // ---- V head: bias + permuted+swizzled store into chunked Vb -----------
    const int hv = (tileN - 2048 + wn) >> 6;
#pragma unroll
    for (int i = 0; i < 4; i++)
#pragma unroll
      for (int j = 0; j < 4; j++) {
        int c = j * 16 + col;
        float bias = bV[hv * 64 + c];
        int m0 = tileM + wm + i * 16 + rq * 4;
        int s0 = m0 & 1023, bb = m0 >> 10;
        int chunk = s0 >> 6, w = s0 & 63, u0 = w & 31;
        int p0 = (u0 & 3) | ((u0 & 16) >> 2) | ((u0 & 8) << 1) | ((u0 & 4) << 1);
        int p = (w & 32) | p0;                 // 4-aligned
        int slot = c * 8 + ((p >> 3) ^ (c & 7));
        short4v s4;
#pragma unroll
        for (int r = 0; r < 4; r++) s4[r] = rnd_bf16(acc[i][j][r] + bias);
        *(short4v*)((short*)Vb +
            ((((size_t)(bb * 32 + hv)) * 17 + chunk) * 512 + slot) * 8 + (p & 7)) = s4;
      }
  }
}

// ---- MFMA flash attention: LDS-staged V, software-pipelined ---------------
__global__ __launch_bounds__(256) void attn_mfma(
    const bf16* __restrict__ Qb, const bf16* __restrict__ Kb,
    const bf16* __restrict__ Vb, bf16* __restrict__ Zb) {
  __shared__ __align__(16) short Vs[4][4096];
  const int flat = blockIdx.x;
  const int xcd = flat & 7, jj = flat >> 3;
  const int hqb = xcd * 8 + (jj & 7);
  const int x = jj >> 3;                    // 0..15
  const int hq = hqb & 31, b = hqb >> 5;
  const int wave = threadIdx.x >> 6, lane = threadIdx.x & 63;
  const int col = lane & 15, quad = lane >> 4;
  const int t = (wave == 0) ? x : (wave == 1) ? 31 - x : (wave == 2) ? 32 + x : 63 - x;
  const int qw = t * 16;

  const bf16x8 qf = *(const bf16x8*)((const short*)Qb +
      (((size_t)(b * 32 + hq)) * 1024 + qw + col) * 32 + quad * 8);
  const short* kbase = (const short*)Kb + ((size_t)(b * 32 + hq)) * 1152 * 32 + quad * 8;
  const short* vbh = (const short*)Vb + ((size_t)(b * 32 + hq)) * (17 * 4096) + lane * 8;
  short* vdst = &Vs[wave][0];

  const int kend = (qw + 32 < 1040) ? qw + 32 : 1040;
  const int nch = (kend + 63) >> 6;

  f32x4 O[4] = {};
  float m = -1e30f, l = 0.f;

  // prologue: K(0) first (older in vmcnt FIFO), then V(0) staging
  bf16x8 kf[4];
#pragma unroll
  for (int mbk = 0; mbk < 4; mbk++)
    kf[mbk] = *(const bf16x8*)(kbase + (size_t)(mbk * 16 + col) * 32);
#pragma unroll
  for (int g = 0; g < 8; g++)
    __builtin_amdgcn_global_load_lds(AS1(vbh + g * 512), AS3(vdst + g * 512), 16, 0, 0);

  for (int ci = 0; ci < nch; ci++) {
    const int kc = ci * 64;
    f32x4 St[4] = {};
#pragma unroll
    for (int mbk = 0; mbk < 4; mbk++)
      St[mbk] = __builtin_amdgcn_mfma_f32_16x16x32_bf16(kf[mbk], qf, St[mbk], 0, 0, 0);
    if (kc + 63 > qw + 16) {
      int qv = qw + col + 16;
#pragma unroll
      for (int mbk = 0; mbk < 4; mbk++)
#pragma unroll
        for (int r = 0; r < 4; r++)
          if (kc + mbk * 16 + quad * 4 + r > qv) St[mbk][r] = -1e30f;
    }
    float cm0 = fmaxf(fmaxf(St[0][0], St[0][1]), fmaxf(St[0][2], St[0][3]));
    float cm1 = fmaxf(fmaxf(St[1][0], St[1][1]), fmaxf(St[1][2], St[1][3]));
    float cm2 = fmaxf(fmaxf(St[2][0], St[2][1]), fmaxf(St[2][2], St[2][3]));
    float cm3 = fmaxf(fmaxf(St[3][0], St[3][1]), fmaxf(St[3][2], St[3][3]));
    float cmax = fmaxf(fmaxf(cm0, cm1), fmaxf(cm2, cm3));
    cmax = fmaxf(cmax, __shfl_xor(cmax, 16));
    cmax = fmaxf(cmax, __shfl_xor(cmax, 32));
    float mn = fmaxf(m, cmax);
    float al = __expf(m - mn);
    m = mn;
    float ps = 0.f;
#pragma unroll
    for (int mbk = 0; mbk < 4; mbk++)
#pragma unroll
      for (int r = 0; r < 4; r++) {
        float p = __expf(St[mbk][r] - mn);
        ps += p;
        St[mbk][r] = p;
      }
    ps += __shfl_xor(ps, 16);
    ps += __shfl_xor(ps, 32);
    l = l * al + ps;
    int4v pi[2];
#pragma unroll
    for (int pr = 0; pr < 2; pr++)
#pragma unroll
      for (int d = 0; d < 4; d++)
        pi[pr][d] = pack_bf16_pair(St[2 * pr + (d >> 1)][(d & 1) * 2 + 1],
                                   St[2 * pr + (d >> 1)][(d & 1) * 2]);
#pragma unroll
    for (int cb = 0; cb < 4; cb++)
#pragma unroll
      for (int r = 0; r < 4; r++) O[cb][r] *= al;
    asm volatile("s_waitcnt vmcnt(0)" ::: "memory");
    bf16x8 vf[2][4];
#pragma unroll
    for (int ks = 0; ks < 2; ks++)
#pragma unroll
      for (int cb = 0; cb < 4; cb++) {
        int slot = (cb * 16 + col) * 8 + ((ks * 4 + quad) ^ (col & 7));
        vf[ks][cb] = *(const bf16x8*)(vdst + slot * 8);
      }
    asm volatile("s_waitcnt lgkmcnt(0)" ::: "memory");   // WAR guard vs restage
    if (ci + 1 < nch) {
      const int kn = kc + 64;
#pragma unroll
      for (int mbk = 0; mbk < 4; mbk++)
        kf[mbk] = *(const bf16x8*)(kbase + (size_t)(kn + mbk * 16 + col) * 32);
      const short* vsrc = vbh + (ci + 1) * 4096;
#pragma unroll
      for (int g = 0; g < 8; g++)
        __builtin_amdgcn_global_load_lds(AS1(vsrc + g * 512), AS3(vdst + g * 512), 16, 0, 0);
    }
#pragma unroll
    for (int ks = 0; ks < 2; ks++) {
      bf16x8 prs = *(bf16x8*)&pi[ks];
#pragma unroll
      for (int cb = 0; cb < 4; cb++)
        O[cb] = __builtin_amdgcn_mfma_f32_16x16x32_bf16(vf[ks][cb], prs, O[cb], 0, 0, 0);
    }
  }
  float inv = 1.f / l;
  short* zrow = (short*)Zb + ((size_t)(b * 1024 + qw + col)) * 2048 + hq * 64 + quad * 4;
#pragma unroll
  for (int cb = 0; cb < 4; cb++) {
    short4v s4;
#pragma unroll
    for (int r = 0; r < 4; r++) s4[r] = rnd_bf16(O[cb][r] * inv);
    *(short4v*)(zrow + cb * 16) = s4;
  }
}

// ---- GEMM2: 128(M) x 64(N) tiles, 256 blocks, XCD-swizzled ----------------
__global__ __launch_bounds__(256) void gemm2_wide(
    const bf16* __restrict__ A, const bf16* __restrict__ Bt, float* __restrict__ C) {
  __shared__ __align__(16) short As[128 * 32];
  __shared__ __align__(16) short Bs[64 * 32];
  // xcd owns 2 M-bands x all 16 N-tiles: A-tile stays in its L2
  const int flat = blockIdx.x;
  const int xcd = flat & 7, idx = flat >> 3;          // idx 0..31
  const int tileM = (xcd * 2 + (idx >> 4)) * 128;
  const int tileN = (idx & 15) * 64;
  const int tid = threadIdx.x, wave = tid >> 6, lane = tid & 63;
  const int wm = (wave >> 1) * 64, wn = (wave & 1) * 32;
  const int mrow = lane & 15, kq = lane >> 4;
  f32x4 acc[4][2] = {};

  for (int k0 = 0; k0 < 2048; k0 += 32) {
#pragma unroll
    for (int i = 0; i < 2; i++) {                 // A: 512 chunks
      int c = (wave * 2 + i) * 64 + lane;
      int row = c >> 2, ko = (c & 3) * 8;
      const short* ga = (const short*)A + (size_t)(tileM + row) * 2048 + k0 + ko;
      __builtin_amdgcn_global_load_lds(AS1(ga), AS3(&As[(wave * 2 + i) * 512]), 16, 0, 0);
    }
    {                                             // B: 256 chunks
      int c = wave * 64 + lane;
      int row = c >> 2, ko = (c & 3) * 8;
      const short* gb = (const short*)Bt + (size_t)(tileN + row) * 2048 + k0 + ko;
      __builtin_amdgcn_global_load_lds(AS1(gb), AS3(&Bs[wave * 512]), 16, 0, 0);
    }
    __syncthreads();
    bf16x8 af[4], bfr[2];
#pragma unroll
    for (int t = 0; t < 4; t++) af[t] = *(const bf16x8*)&As[(wm + t * 16 + mrow) * 32 + kq * 8];
#pragma unroll
    for (int t = 0; t < 2; t++) bfr[t] = *(const bf16x8*)&Bs[(wn + t * 16 + mrow) * 32 + kq * 8];
#pragma unroll
    for (int i = 0; i < 4; i++)
#pragma unroll
      for (int j = 0; j < 2; j++)
        acc[i][j] = __builtin_amdgcn_mfma_f32_16x16x32_bf16(af[i], bfr[j], acc[i][j], 0, 0, 0);
    __syncthreads();
  }
  const int col = lane & 15, rq = lane >> 4;
#pragma unroll
  for (int i = 0; i < 4; i++)
#pragma unroll
    for (int j = 0; j < 2; j++)
#pragma unroll
      for (int r = 0; r < 4; r++) {
        int mm = tileM + wm + i * 16 + rq * 4 + r;
        int nn = tileN + wn + j * 16 + col;
        C[(size_t)mm * 1024 + nn] = acc[i][j][r];
      }
}

// ---------------------------------------------------------------------------
extern "C" void kernel_launch(void* const* d_in, const int* in_sizes, int n_in,
                              void* d_out, int out_size, void* d_ws, size_t ws_size,
                              hipStream_t stream) {
  const float* resid = (const float*)d_in[0];
  const float* WQ = (const float*)d_in[1];
  const float* WK = (const float*)d_in[2];
  const float* WV = (const float*)d_in[3];
  const float* WO = (const float*)d_in[4];
  const float* bQ = (const float*)d_in[5];
  const float* bK = (const float*)d_in[6];
  const float* bV = (const float*)d_in[7];
  const float* vk = (const float*)d_in[8];
  const float* vv = (const float*)d_in[9];
  float* out = (float*)d_out;

  // workspace layout, no aliasing (~41.5 MB):
  char* ws = (char*)d_ws;
  bf16* A_bf = (bf16*)(ws);                 // 4 MB   [2048][1024]
  bf16* Wt   = (bf16*)(ws + 4194304);       // 8 MB   [4096][1024]
  bf16* Wot  = (bf16*)(ws + 12582912);      // 4 MB   [1024][2048]
  bf16* Qb   = (bf16*)(ws + 16777216);      // 4 MB   [(b,h)][1024][32] scaled
  bf16* Kb   = (bf16*)(ws + 20971520);      // 4.5 MB [(b,h)][1152][32]
  bf16* Vb   = (bf16*)(ws + 25690112);      // 8.5 MB [(b,h)][17][512 slots][8]
  bf16* Zb   = (bf16*)(ws + 35127296);      // 8 MB   [2048][2048]

  prep<<<8704, 256, 0, stream>>>(resid, WV, WQ, WK, WO, vk, vv, A_bf, Wt, Wot, Kb, Vb);
  gemm1_fused<<<512, 256, 0, stream>>>(A_bf, Wt, bQ, bK, bV, Qb, Kb, Vb);
  attn_mfma<<<1024, 256, 0, stream>>>(Qb, Kb, Vb, Zb);
  gemm2_wide<<<256, 256, 0, stream>>>(Zb, Wot, out);
}

// Round 9
// 175.154 us; speedup vs baseline: 1.0486x; 1.0486x over previous
//
#include <hip/hip_runtime.h>
#include <hip/hip_bf16.h>
#include <math.h>

// ---------------------------------------------------------------------------
// LowRankSparseAttention on MI355X (gfx950)
//   1. prep: cvt resid->A_bf, cvt W_V->Wt rows 2048+, virtual K/V fills,
//      transpose W_Q/W_K->Wt, transpose W_O->Wot
//   2. gemm1_fused (128x128): QKV proj, fused epilogue (QK tiles use swapped
//      mfma operands -> coalesced short4 stores; V permuted+swizzled chunks)
//   3. attn_mfma: PAIRED-TILE flash attn: wave owns tiles (x, 63-x) whose
//      chunk ranges nest; K/V loaded once per chunk for both tiles; two
//      online-softmax chains (ILP); V ping-pong LDS staging -> Zb bf16
//   4. gemm2 (64x64 tiles, 512 blocks): out[2048x1024] f32 = Zb @ Wot^T
// ---------------------------------------------------------------------------

typedef short bf16x8 __attribute__((ext_vector_type(8)));
typedef short short4v __attribute__((ext_vector_type(4)));
typedef float f32x4 __attribute__((ext_vector_type(4)));
typedef int int4v __attribute__((ext_vector_type(4)));
typedef __hip_bfloat16 bf16;

#define AS1(p) ((const __attribute__((address_space(1))) void*)(const void*)(p))
#define AS3(p) ((__attribute__((address_space(3))) void*)(void*)(p))

static constexpr float INV_SCALE = 0.17677669529663687f;  // 1/sqrt(32)

// fast RNE f32->bf16 (finite values only): 4 int ops
__device__ inline short rnd_bf16(float x) {
  unsigned u = __float_as_uint(x);
  return (short)((u + 0x7fffu + ((u >> 16) & 1u)) >> 16);
}

// pack two positive f32 -> dword of bf16 pair (round half-up)
__device__ inline int pack_bf16_pair(float hi, float lo) {
  unsigned a = __float_as_uint(hi) + 0x8000u;
  unsigned b = __float_as_uint(lo) + 0x8000u;
  return (int)__builtin_amdgcn_perm(a, b, 0x07060302u);
}

// ---- merged preprocessing kernel ------------------------------------------
__global__ __launch_bounds__(256) void prep(
    const float* __restrict__ resid, const float* __restrict__ WV,
    const float* __restrict__ WQ, const float* __restrict__ WK,
    const float* __restrict__ WO, const float* __restrict__ vk,
    const float* __restrict__ vv,
    bf16* __restrict__ A_bf, bf16* __restrict__ Wt, bf16* __restrict__ Wot,
    bf16* __restrict__ Kb, bf16* __restrict__ Vb) {
  __shared__ float t[64][65];
  const int blk = blockIdx.x, tid = threadIdx.x;
  if (blk < 4096) {
    const float* src = (blk < 2048) ? resid : WV;
    short* dst = (short*)((blk < 2048) ? A_bf : (Wt + (size_t)2048 * 1024));
    int i = ((blk & 2047) * 256 + tid) * 4;
    float4 v = *(const float4*)(src + i);
    dst[i + 0] = rnd_bf16(v.x); dst[i + 1] = rnd_bf16(v.y);
    dst[i + 2] = rnd_bf16(v.z); dst[i + 3] = rnd_bf16(v.w);
  } else if (blk < 7168) {
    int idx = (blk - 4096) * 256 + tid;
    if (idx < 262144) {              // Kb virtual: toks 1024..1151 per (b,h)
      int b = idx >> 17, rem = idx & 131071;
      int j = rem >> 10, c = rem & 1023;     // c = h*32+d
      int h = c >> 5, d = c & 31;
      float v = (j < 16) ? vk[j * 1024 + c] : 0.f;
      Kb[(((size_t)(b * 32 + h)) * 1152 + 1024 + j) * 32 + d] = __float2bfloat16(v);
    } else if (idx < 524288) {       // Vb virtual: chunk 16 (toks 1024..1087)
      int i2 = idx - 262144;         // [0, 262144): 2 b x 2048 ch x 64 p
      int b = i2 >> 17, rem = i2 & 131071;
      int ch = rem >> 6, p = rem & 63;
      int pl = p & 31;
      int u = (p & 32) | ((pl & 4) << 2) | ((pl & 24) >> 1) | (pl & 3);
      float v = (u < 16) ? vv[(size_t)u * 2048 + ch] : 0.f;
      int hv = ch >> 6, c = ch & 63;
      int slot = c * 8 + ((p >> 3) ^ (c & 7));
      Vb[((((size_t)(b * 32 + hv)) * 17 + 16) * 512 + slot) * 8 + (p & 7)] = __float2bfloat16(v);
    }
  } else if (blk < 8192) {
    int i = blk - 7168;
    int mt = i & 15, h = (i >> 4) & 31, qk = i >> 9;
    const float* W = qk ? WK : WQ;
    const int m0 = mt * 64;
    for (int idx = tid; idx < 64 * 32; idx += 256) {
      int ii = idx >> 5, d = idx & 31;
      t[ii][d] = W[((size_t)h * 1024 + m0 + ii) * 32 + d];
    }
    __syncthreads();
    const int rowbase = qk * 1024 + h * 32;
    for (int idx = tid; idx < 32 * 64; idx += 256) {
      int d = idx >> 6, ii = idx & 63;
      Wt[(size_t)(rowbase + d) * 1024 + m0 + ii] = __float2bfloat16(t[ii][d]);
    }
  } else {
    int i = blk - 8192;
    int h0 = (i & 31) * 64, m0 = (i >> 5) * 64;
    for (int idx = tid; idx < 64 * 64; idx += 256) {
      int ii = idx >> 6, j = idx & 63;
      t[ii][j] = WO[(size_t)(h0 + ii) * 1024 + m0 + j];
    }
    __syncthreads();
    for (int idx = tid; idx < 64 * 64; idx += 256) {
      int ii = idx >> 6, j = idx & 63;
      Wot[(size_t)(m0 + ii) * 2048 + h0 + j] = __float2bfloat16(t[j][ii]);
    }
  }
}

// ---- GEMM1 + fused epilogue: 128(tok) x 128(feat) tiles, K=1024 -----------
__global__ __launch_bounds__(256) void gemm1_fused(
    const bf16* __restrict__ A, const bf16* __restrict__ Bt,
    const float* __restrict__ bQ, const float* __restrict__ bK,
    const float* __restrict__ bV,
    bf16* __restrict__ Qb, bf16* __restrict__ Kb, bf16* __restrict__ Vb) {
  __shared__ __align__(16) short As[128 * 32];
  __shared__ __align__(16) short Bs[128 * 32];
  const int flat = blockIdx.x;
  const int xcd = flat & 7, idx = flat >> 3;          // idx 0..63
  const int tileM = (xcd * 2 + (idx >> 5)) * 128;     // token band
  const int tileN = (idx & 31) * 128;                 // feature tile
  const int tid = threadIdx.x, wave = tid >> 6, lane = tid & 63;
  const int wm = (wave >> 1) * 64, wn = (wave & 1) * 64;
  const int mrow = lane & 15, kq = lane >> 4;
  const bool isQK = tileN < 2048;
  f32x4 acc[4][4] = {};

  for (int k0 = 0; k0 < 1024; k0 += 32) {
#pragma unroll
    for (int i = 0; i < 2; i++) {
      int c = (wave * 2 + i) * 64 + lane;
      int row = c >> 2, ko = (c & 3) * 8;
      const short* ga = (const short*)A + (size_t)(tileM + row) * 1024 + k0 + ko;
      const short* gb = (const short*)Bt + (size_t)(tileN + row) * 1024 + k0 + ko;
      __builtin_amdgcn_global_load_lds(AS1(ga), AS3(&As[(wave * 2 + i) * 512]), 16, 0, 0);
      __builtin_amdgcn_global_load_lds(AS1(gb), AS3(&Bs[(wave * 2 + i) * 512]), 16, 0, 0);
    }
    __syncthreads();
    bf16x8 af[4], bfr[4];
#pragma unroll
    for (int t = 0; t < 4; t++) {
      af[t]  = *(const bf16x8*)&As[(wm + t * 16 + mrow) * 32 + kq * 8];
      bfr[t] = *(const bf16x8*)&Bs[(wn + t * 16 + mrow) * 32 + kq * 8];
    }
    if (isQK) {
#pragma unroll
      for (int fj = 0; fj < 4; fj++)
#pragma unroll
        for (int ti = 0; ti < 4; ti++)
          acc[fj][ti] = __builtin_amdgcn_mfma_f32_16x16x32_bf16(bfr[fj], af[ti], acc[fj][ti], 0, 0, 0);
    } else {
#pragma unroll
      for (int i = 0; i < 4; i++)
#pragma unroll
        for (int j = 0; j < 4; j++)
          acc[i][j] = __builtin_amdgcn_mfma_f32_16x16x32_bf16(af[i], bfr[j], acc[i][j], 0, 0, 0);
    }
    __syncthreads();
  }

  const int col = lane & 15, rq = lane >> 4;
  if (isQK) {
    const int qk = tileN >> 10;
    const float* bias = qk ? bK : bQ;
    const int hA = ((tileN & 1023) + wn) >> 5;
    const int d0 = rq * 4;
    const float4 bA0 = *(const float4*)&bias[hA * 32 + d0];
    const float4 bA1 = *(const float4*)&bias[hA * 32 + 16 + d0];
    const float4 bB0 = *(const float4*)&bias[(hA + 1) * 32 + d0];
    const float4 bB1 = *(const float4*)&bias[(hA + 1) * 32 + 16 + d0];
    float invf[4];
#pragma unroll
    for (int r = 0; r < 4; r++)
      invf[r] = exp2f((d0 + r) * -0.8304820237218406f);  // -log2(10000)/16
    const float osc = qk ? 1.f : INV_SCALE;
#pragma unroll
    for (int ti = 0; ti < 4; ti++) {
      int sg = tileM + wm + ti * 16 + col;
      int s = sg & 1023, bb = sg >> 10;
      float sv[4], cv[4];
#pragma unroll
      for (int r = 0; r < 4; r++) __sincosf((float)s * invf[r], &sv[r], &cv[r]);
#pragma unroll
      for (int p = 0; p < 2; p++) {
        int h = hA + p;
        short4v z0, z1;
#pragma unroll
        for (int r = 0; r < 4; r++) {
          float x0 = acc[2 * p][ti][r]     + (p ? (&bB0.x)[r] : (&bA0.x)[r]);
          float x1 = acc[2 * p + 1][ti][r] + (p ? (&bB1.x)[r] : (&bA1.x)[r]);
          float y0 = (x0 * cv[r] - x1 * sv[r]) * osc;
          float y1 = (x1 * cv[r] + x0 * sv[r]) * osc;
          z0[r] = rnd_bf16(y0); z1[r] = rnd_bf16(y1);
        }
        short* dst = qk
            ? (short*)Kb + ((size_t)(bb * 32 + h) * 1152 + s) * 32
            : (short*)Qb + ((size_t)(bb * 32 + h) * 1024 + s) * 32;
        *(short4v*)(dst + d0) = z0;
        *(short4v*)(dst + 16 + d0) = z1;
      }
    }
  } else {
    const int hv = (tileN - 2048 + wn) >> 6;
#pragma unroll
    for (int i = 0; i < 4; i++)
#pragma unroll
      for (int j = 0; j < 4; j++) {
        int c = j * 16 + col;
        float bias = bV[hv * 64 + c];
        int m0 = tileM + wm + i * 16 + rq * 4;
        int s0 = m0 & 1023, bb = m0 >> 10;
        int chunk = s0 >> 6, w = s0 & 63, u0 = w & 31;
        int p0 = (u0 & 3) | ((u0 & 16) >> 2) | ((u0 & 8) << 1) | ((u0 & 4) << 1);
        int p = (w & 32) | p0;                 // 4-aligned
        int slot = c * 8 + ((p >> 3) ^ (c & 7));
        short4v s4;
#pragma unroll
        for (int r = 0; r < 4; r++) s4[r] = rnd_bf16(acc[i][j][r] + bias);
        *(short4v*)((short*)Vb +
            ((((size_t)(bb * 32 + hv)) * 17 + chunk) * 512 + slot) * 8 + (p & 7)) = s4;
      }
  }
}

// ---- PAIRED-TILE flash attention ------------------------------------------
// Wave owns tiles tA = pairIdx (0..31) and tB = 63-pairIdx. A's chunk range
// nests inside B's; K frags and the LDS-staged V chunk serve both tiles.
// Two independent online-softmax chains per wave (ILP). V ping-pong buffers
// (2 x 8KB per wave) remove the restage WAR stall. 512 blocks (2/CU, LDS
// 64KB/block -> exactly resident). XCD swizzle: flat&7 owns 8 (hq,b) pairs.
__global__ __launch_bounds__(256) void attn_mfma(
    const bf16* __restrict__ Qb, const bf16* __restrict__ Kb,
    const bf16* __restrict__ Vb, bf16* __restrict__ Zb) {
  __shared__ __align__(16) short Vs[4][2][4096];
  const int flat = blockIdx.x;                 // 0..511
  const int xcd = flat & 7;
  const int hqb = xcd * 8 + ((flat >> 3) & 7);
  const int xblk = flat >> 6;                  // 0..7
  const int hq = hqb & 31, b = hqb >> 5;
  const int wave = threadIdx.x >> 6, lane = threadIdx.x & 63;
  const int col = lane & 15, quad = lane >> 4;
  const int pairIdx = xblk * 4 + wave;         // 0..31
  const int qwA = pairIdx * 16, qwB = (63 - pairIdx) * 16;

  const short* qbase = (const short*)Qb + ((size_t)(b * 32 + hq)) * 1024 * 32;
  const bf16x8 qfA = *(const bf16x8*)(qbase + (qwA + col) * 32 + quad * 8);
  const bf16x8 qfB = *(const bf16x8*)(qbase + (qwB + col) * 32 + quad * 8);
  const short* kbase = (const short*)Kb + ((size_t)(b * 32 + hq)) * 1152 * 32 + quad * 8;
  const short* vbh = (const short*)Vb + ((size_t)(b * 32 + hq)) * (17 * 4096) + lane * 8;

  const int kendA = qwA + 32;                           // <= 528, < 1040
  const int nchA = (kendA + 63) >> 6;
  const int kendB = (qwB + 32 < 1040) ? qwB + 32 : 1040;
  const int nchB = (kendB + 63) >> 6;                   // nchA <= nchB

  f32x4 OA[4] = {}, OB[4] = {};
  float mA = -1e30f, lA = 0.f, mB = -1e30f, lB = 0.f;

  // prologue: stage V(0) -> buf0, load K(0)
  bf16x8 kf[4];
#pragma unroll
  for (int mbk = 0; mbk < 4; mbk++)
    kf[mbk] = *(const bf16x8*)(kbase + (size_t)(mbk * 16 + col) * 32);
  {
    short* vd = &Vs[wave][0][0];
#pragma unroll
    for (int g = 0; g < 8; g++)
      __builtin_amdgcn_global_load_lds(AS1(vbh + g * 512), AS3(vd + g * 512), 16, 0, 0);
  }

  for (int ci = 0; ci < nchB; ci++) {
    const int kc = ci * 64;
    const bool aAct = ci < nchA;
    // ---- S^T = K @ Q^T for both tiles ----
    f32x4 SB[4] = {};
#pragma unroll
    for (int mbk = 0; mbk < 4; mbk++)
      SB[mbk] = __builtin_amdgcn_mfma_f32_16x16x32_bf16(kf[mbk], qfB, SB[mbk], 0, 0, 0);
    f32x4 SA[4] = {};
    if (aAct) {
#pragma unroll
      for (int mbk = 0; mbk < 4; mbk++)
        SA[mbk] = __builtin_amdgcn_mfma_f32_16x16x32_bf16(kf[mbk], qfA, SA[mbk], 0, 0, 0);
    }
    // ---- masks (boundary chunks only; wave-uniform branches) ----
    if (kc + 63 > qwB + 16) {
      int qv = qwB + col + 16;
#pragma unroll
      for (int mbk = 0; mbk < 4; mbk++)
#pragma unroll
        for (int r = 0; r < 4; r++)
          if (kc + mbk * 16 + quad * 4 + r > qv) SB[mbk][r] = -1e30f;
    }
    if (aAct && kc + 63 > qwA + 16) {
      int qv = qwA + col + 16;
#pragma unroll
      for (int mbk = 0; mbk < 4; mbk++)
#pragma unroll
        for (int r = 0; r < 4; r++)
          if (kc + mbk * 16 + quad * 4 + r > qv) SA[mbk][r] = -1e30f;
    }
    // ---- online softmax, chain B ----
    int4v piB[2], piA[2];
    {
      float c0 = fmaxf(fmaxf(SB[0][0], SB[0][1]), fmaxf(SB[0][2], SB[0][3]));
      float c1 = fmaxf(fmaxf(SB[1][0], SB[1][1]), fmaxf(SB[1][2], SB[1][3]));
      float c2 = fmaxf(fmaxf(SB[2][0], SB[2][1]), fmaxf(SB[2][2], SB[2][3]));
      float c3 = fmaxf(fmaxf(SB[3][0], SB[3][1]), fmaxf(SB[3][2], SB[3][3]));
      float cmax = fmaxf(fmaxf(c0, c1), fmaxf(c2, c3));
      cmax = fmaxf(cmax, __shfl_xor(cmax, 16));
      cmax = fmaxf(cmax, __shfl_xor(cmax, 32));
      float mn = fmaxf(mB, cmax);
      float al = __expf(mB - mn);
      mB = mn;
      float ps = 0.f;
#pragma unroll
      for (int mbk = 0; mbk < 4; mbk++)
#pragma unroll
        for (int r = 0; r < 4; r++) {
          float p = __expf(SB[mbk][r] - mn);
          ps += p;
          SB[mbk][r] = p;
        }
      ps += __shfl_xor(ps, 16);
      ps += __shfl_xor(ps, 32);
      lB = lB * al + ps;
#pragma unroll
      for (int pr = 0; pr < 2; pr++)
#pragma unroll
        for (int d = 0; d < 4; d++)
          piB[pr][d] = pack_bf16_pair(SB[2 * pr + (d >> 1)][(d & 1) * 2 + 1],
                                      SB[2 * pr + (d >> 1)][(d & 1) * 2]);
#pragma unroll
      for (int cb = 0; cb < 4; cb++)
#pragma unroll
        for (int r = 0; r < 4; r++) OB[cb][r] *= al;
    }
    // ---- online softmax, chain A ----
    if (aAct) {
      float c0 = fmaxf(fmaxf(SA[0][0], SA[0][1]), fmaxf(SA[0][2], SA[0][3]));
      float c1 = fmaxf(fmaxf(SA[1][0], SA[1][1]), fmaxf(SA[1][2], SA[1][3]));
      float c2 = fmaxf(fmaxf(SA[2][0], SA[2][1]), fmaxf(SA[2][2], SA[2][3]));
      float c3 = fmaxf(fmaxf(SA[3][0], SA[3][1]), fmaxf(SA[3][2], SA[3][3]));
      float cmax = fmaxf(fmaxf(c0, c1), fmaxf(c2, c3));
      cmax = fmaxf(cmax, __shfl_xor(cmax, 16));
      cmax = fmaxf(cmax, __shfl_xor(cmax, 32));
      float mn = fmaxf(mA, cmax);
      float al = __expf(mA - mn);
      mA = mn;
      float ps = 0.f;
#pragma unroll
      for (int mbk = 0; mbk < 4; mbk++)
#pragma unroll
        for (int r = 0; r < 4; r++) {
          float p = __expf(SA[mbk][r] - mn);
          ps += p;
          SA[mbk][r] = p;
        }
      ps += __shfl_xor(ps, 16);
      ps += __shfl_xor(ps, 32);
      lA = lA * al + ps;
#pragma unroll
      for (int pr = 0; pr < 2; pr++)
#pragma unroll
        for (int d = 0; d < 4; d++)
          piA[pr][d] = pack_bf16_pair(SA[2 * pr + (d >> 1)][(d & 1) * 2 + 1],
                                      SA[2 * pr + (d >> 1)][(d & 1) * 2]);
#pragma unroll
      for (int cb = 0; cb < 4; cb++)
#pragma unroll
        for (int r = 0; r < 4; r++) OA[cb][r] *= al;
    }
    // ---- V(ci) ready (kf's vmcnt wait drained the older stage) ----
    asm volatile("s_waitcnt vmcnt(0)" ::: "memory");
    const short* vd = &Vs[wave][ci & 1][0];
    bf16x8 vf[2][4];
#pragma unroll
    for (int ks = 0; ks < 2; ks++)
#pragma unroll
      for (int cb = 0; cb < 4; cb++) {
        int slot = (cb * 16 + col) * 8 + ((ks * 4 + quad) ^ (col & 7));
        vf[ks][cb] = *(const bf16x8*)(vd + slot * 8);
      }
    // ---- prefetch K(ci+1); stage V(ci+1) into the other buffer ----
    if (ci + 1 < nchB) {
      const int kn = kc + 64;
#pragma unroll
      for (int mbk = 0; mbk < 4; mbk++)
        kf[mbk] = *(const bf16x8*)(kbase + (size_t)(kn + mbk * 16 + col) * 32);
      const short* vsrc = vbh + (ci + 1) * 4096;
      short* vdn = &Vs[wave][(ci + 1) & 1][0];
#pragma unroll
      for (int g = 0; g < 8; g++)
        __builtin_amdgcn_global_load_lds(AS1(vsrc + g * 512), AS3(vdn + g * 512), 16, 0, 0);
    }
    // ---- O^T += V^T @ P for both tiles ----
#pragma unroll
    for (int ks = 0; ks < 2; ks++) {
      bf16x8 prB = *(bf16x8*)&piB[ks];
#pragma unroll
      for (int cb = 0; cb < 4; cb++)
        OB[cb] = __builtin_amdgcn_mfma_f32_16x16x32_bf16(vf[ks][cb], prB, OB[cb], 0, 0, 0);
    }
    if (aAct) {
#pragma unroll
      for (int ks = 0; ks < 2; ks++) {
        bf16x8 prA = *(bf16x8*)&piA[ks];
#pragma unroll
        for (int cb = 0; cb < 4; cb++)
          OA[cb] = __builtin_amdgcn_mfma_f32_16x16x32_bf16(vf[ks][cb], prA, OA[cb], 0, 0, 0);
      }
    }
  }
  // ---- epilogue: both tiles ----
  {
    float inv = 1.f / lA;
    short* zrow = (short*)Zb + ((size_t)(b * 1024 + qwA + col)) * 2048 + hq * 64 + quad * 4;
#pragma unroll
    for (int cb = 0; cb < 4; cb++) {
      short4v s4;
#pragma unroll
      for (int r = 0; r < 4; r++) s4[r] = rnd_bf16(OA[cb][r] * inv);
      *(short4v*)(zrow + cb * 16) = s4;
    }
  }
  {
    float inv = 1.f / lB;
    short* zrow = (short*)Zb + ((size_t)(b * 1024 + qwB + col)) * 2048 + hq * 64 + quad * 4;
#pragma unroll
    for (int cb = 0; cb < 4; cb++) {
      short4v s4;
#pragma unroll
      for (int r = 0; r < 4; r++) s4[r] = rnd_bf16(OB[cb][r] * inv);
      *(short4v*)(zrow + cb * 16) = s4;
    }
  }
}

// ---- GEMM2: 64x64 tiles, 512 blocks, f32 out: out = Zb @ Wot^T ------------
__global__ __launch_bounds__(256) void gemm2_small(
    const bf16* __restrict__ A, const bf16* __restrict__ Bt, float* __restrict__ C,
    int K, int ldc) {
  __shared__ __align__(16) short As[64 * 32];
  __shared__ __align__(16) short Bs[64 * 32];
  const int tileM = blockIdx.y * 64, tileN = blockIdx.x * 64;
  const int tid = threadIdx.x, wave = tid >> 6, lane = tid & 63;
  const int wm = (wave >> 1) * 32, wn = (wave & 1) * 32;
  const int mrow = lane & 15, kq = lane >> 4;
  f32x4 acc[2][2] = {};

  for (int k0 = 0; k0 < K; k0 += 32) {
    {
      int c = wave * 64 + lane;
      int row = c >> 2, ko = (c & 3) * 8;
      const short* ga = (const short*)A + (size_t)(tileM + row) * K + k0 + ko;
      __builtin_amdgcn_global_load_lds(AS1(ga), AS3(&As[wave * 512]), 16, 0, 0);
    }
    {
      int c = wave * 64 + lane;
      int row = c >> 2, ko = (c & 3) * 8;
      const short* gb = (const short*)Bt + (size_t)(tileN + row) * K + k0 + ko;
      __builtin_amdgcn_global_load_lds(AS1(gb), AS3(&Bs[wave * 512]), 16, 0, 0);
    }
    __syncthreads();
    bf16x8 af[2], bfr[2];
#pragma unroll
    for (int t = 0; t < 2; t++) {
      af[t]  = *(const bf16x8*)&As[(wm + t * 16 + mrow) * 32 + kq * 8];
      bfr[t] = *(const bf16x8*)&Bs[(wn + t * 16 + mrow) * 32 + kq * 8];
    }
#pragma unroll
    for (int i = 0; i < 2; i++)
#pragma unroll
      for (int j = 0; j < 2; j++)
        acc[i][j] = __builtin_amdgcn_mfma_f32_16x16x32_bf16(af[i], bfr[j], acc[i][j], 0, 0, 0);
    __syncthreads();
  }
  const int col = lane & 15, rq = lane >> 4;
#pragma unroll
  for (int i = 0; i < 2; i++)
#pragma unroll
    for (int j = 0; j < 2; j++)
#pragma unroll
      for (int r = 0; r < 4; r++) {
        int mm = tileM + wm + i * 16 + rq * 4 + r;
        int nn = tileN + wn + j * 16 + col;
        C[(size_t)mm * ldc + nn] = acc[i][j][r];
      }
}

// ---------------------------------------------------------------------------
extern "C" void kernel_launch(void* const* d_in, const int* in_sizes, int n_in,
                              void* d_out, int out_size, void* d_ws, size_t ws_size,
                              hipStream_t stream) {
  const float* resid = (const float*)d_in[0];
  const float* WQ = (const float*)d_in[1];
  const float* WK = (const float*)d_in[2];
  const float* WV = (const float*)d_in[3];
  const float* WO = (const float*)d_in[4];
  const float* bQ = (const float*)d_in[5];
  const float* bK = (const float*)d_in[6];
  const float* bV = (const float*)d_in[7];
  const float* vk = (const float*)d_in[8];
  const float* vv = (const float*)d_in[9];
  float* out = (float*)d_out;

  // workspace layout, no aliasing (~41.5 MB):
  char* ws = (char*)d_ws;
  bf16* A_bf = (bf16*)(ws);                 // 4 MB   [2048][1024]
  bf16* Wt   = (bf16*)(ws + 4194304);       // 8 MB   [4096][1024]
  bf16* Wot  = (bf16*)(ws + 12582912);      // 4 MB   [1024][2048]
  bf16* Qb   = (bf16*)(ws + 16777216);      // 4 MB   [(b,h)][1024][32] scaled
  bf16* Kb   = (bf16*)(ws + 20971520);      // 4.5 MB [(b,h)][1152][32]
  bf16* Vb   = (bf16*)(ws + 25690112);      // 8.5 MB [(b,h)][17][512 slots][8]
  bf16* Zb   = (bf16*)(ws + 35127296);      // 8 MB   [2048][2048]

  prep<<<8704, 256, 0, stream>>>(resid, WV, WQ, WK, WO, vk, vv, A_bf, Wt, Wot, Kb, Vb);
  gemm1_fused<<<512, 256, 0, stream>>>(A_bf, Wt, bQ, bK, bV, Qb, Kb, Vb);
  attn_mfma<<<512, 256, 0, stream>>>(Qb, Kb, Vb, Zb);
  gemm2_small<<<dim3(16, 32), 256, 0, stream>>>(Zb, Wot, out, 2048, 1024);
}

// Round 10
// 163.899 us; speedup vs baseline: 1.1206x; 1.0687x over previous
//
#include <hip/hip_runtime.h>
#include <hip/hip_bf16.h>
#include <math.h>

// ---------------------------------------------------------------------------
// LowRankSparseAttention on MI355X (gfx950)
//   1. prep: cvt resid->A_bf, cvt W_V->Wt rows 2048+, virtual K/V fills,
//      transpose W_Q/W_K->Wt, transpose W_O->Wot
//   2. gemm1_fused (128x128 tile, BK=64, swizzled LDS): QKV proj + fused
//      epilogue (QK: swapped-operand mfma -> coalesced short4 stores with
//      rotary in-lane; V: permuted+swizzled chunk store)
//   3. attn_mfma: paired-tile flash attn (wave owns tiles x and 63-x; K/V
//      loaded once per chunk for both; two online-softmax chains; V ping-pong
//      LDS staging) -> Zb bf16
//   4. gemm2 (64x64 tile, BK=64, swizzled LDS, 512 blocks): out = Zb @ Wot^T
// BK=64 rationale: m97-structure stall is the vmcnt(0)+s_barrier drain per
// K-step; BK=64 halves barrier count at unchanged LDS-occupancy (32/16 KB).
// 128-B LDS rows alias banks, so staging XOR-swizzles source chunks
// (g = j ^ (row&7)); frag reads un-swizzle -> 2-way conflicts only (free).
// ---------------------------------------------------------------------------

typedef short bf16x8 __attribute__((ext_vector_type(8)));
typedef short short4v __attribute__((ext_vector_type(4)));
typedef float f32x4 __attribute__((ext_vector_type(4)));
typedef int int4v __attribute__((ext_vector_type(4)));
typedef __hip_bfloat16 bf16;

#define AS1(p) ((const __attribute__((address_space(1))) void*)(const void*)(p))
#define AS3(p) ((__attribute__((address_space(3))) void*)(void*)(p))

static constexpr float INV_SCALE = 0.17677669529663687f;  // 1/sqrt(32)

// fast RNE f32->bf16 (finite values only): 4 int ops
__device__ inline short rnd_bf16(float x) {
  unsigned u = __float_as_uint(x);
  return (short)((u + 0x7fffu + ((u >> 16) & 1u)) >> 16);
}

// pack two positive f32 -> dword of bf16 pair (round half-up)
__device__ inline int pack_bf16_pair(float hi, float lo) {
  unsigned a = __float_as_uint(hi) + 0x8000u;
  unsigned b = __float_as_uint(lo) + 0x8000u;
  return (int)__builtin_amdgcn_perm(a, b, 0x07060302u);
}

// ---- merged preprocessing kernel ------------------------------------------
__global__ __launch_bounds__(256) void prep(
    const float* __restrict__ resid, const float* __restrict__ WV,
    const float* __restrict__ WQ, const float* __restrict__ WK,
    const float* __restrict__ WO, const float* __restrict__ vk,
    const float* __restrict__ vv,
    bf16* __restrict__ A_bf, bf16* __restrict__ Wt, bf16* __restrict__ Wot,
    bf16* __restrict__ Kb, bf16* __restrict__ Vb) {
  __shared__ float t[64][65];
  const int blk = blockIdx.x, tid = threadIdx.x;
  if (blk < 4096) {
    const float* src = (blk < 2048) ? resid : WV;
    short* dst = (short*)((blk < 2048) ? A_bf : (Wt + (size_t)2048 * 1024));
    int i = ((blk & 2047) * 256 + tid) * 4;
    float4 v = *(const float4*)(src + i);
    dst[i + 0] = rnd_bf16(v.x); dst[i + 1] = rnd_bf16(v.y);
    dst[i + 2] = rnd_bf16(v.z); dst[i + 3] = rnd_bf16(v.w);
  } else if (blk < 7168) {
    int idx = (blk - 4096) * 256 + tid;
    if (idx < 262144) {              // Kb virtual: toks 1024..1151 per (b,h)
      int b = idx >> 17, rem = idx & 131071;
      int j = rem >> 10, c = rem & 1023;     // c = h*32+d
      int h = c >> 5, d = c & 31;
      float v = (j < 16) ? vk[j * 1024 + c] : 0.f;
      Kb[(((size_t)(b * 32 + h)) * 1152 + 1024 + j) * 32 + d] = __float2bfloat16(v);
    } else if (idx < 524288) {       // Vb virtual: chunk 16 (toks 1024..1087)
      int i2 = idx - 262144;         // [0, 262144): 2 b x 2048 ch x 64 p
      int b = i2 >> 17, rem = i2 & 131071;
      int ch = rem >> 6, p = rem & 63;
      int pl = p & 31;
      int u = (p & 32) | ((pl & 4) << 2) | ((pl & 24) >> 1) | (pl & 3);
      float v = (u < 16) ? vv[(size_t)u * 2048 + ch] : 0.f;
      int hv = ch >> 6, c = ch & 63;
      int slot = c * 8 + ((p >> 3) ^ (c & 7));
      Vb[((((size_t)(b * 32 + hv)) * 17 + 16) * 512 + slot) * 8 + (p & 7)] = __float2bfloat16(v);
    }
  } else if (blk < 8192) {
    int i = blk - 7168;
    int mt = i & 15, h = (i >> 4) & 31, qk = i >> 9;
    const float* W = qk ? WK : WQ;
    const int m0 = mt * 64;
    for (int idx = tid; idx < 64 * 32; idx += 256) {
      int ii = idx >> 5, d = idx & 31;
      t[ii][d] = W[((size_t)h * 1024 + m0 + ii) * 32 + d];
    }
    __syncthreads();
    const int rowbase = qk * 1024 + h * 32;
    for (int idx = tid; idx < 32 * 64; idx += 256) {
      int d = idx >> 6, ii = idx & 63;
      Wt[(size_t)(rowbase + d) * 1024 + m0 + ii] = __float2bfloat16(t[ii][d]);
    }
  } else {
    int i = blk - 8192;
    int h0 = (i & 31) * 64, m0 = (i >> 5) * 64;
    for (int idx = tid; idx < 64 * 64; idx += 256) {
      int ii = idx >> 6, j = idx & 63;
      t[ii][j] = WO[(size_t)(h0 + ii) * 1024 + m0 + j];
    }
    __syncthreads();
    for (int idx = tid; idx < 64 * 64; idx += 256) {
      int ii = idx >> 6, j = idx & 63;
      Wot[(size_t)(m0 + ii) * 2048 + h0 + j] = __float2bfloat16(t[j][ii]);
    }
  }
}

// ---- GEMM1 + fused epilogue: 128x128 tile, BK=64, K=1024 ------------------
// LDS: [128 rows][64 cols] bf16, 8 chunks(16B)/row; LDS pos (row,j) holds
// global chunk j^(row&7). Frag read un-swizzles. 16 K-iters, 32 mfma/iter.
__global__ __launch_bounds__(256) void gemm1_fused(
    const bf16* __restrict__ A, const bf16* __restrict__ Bt,
    const float* __restrict__ bQ, const float* __restrict__ bK,
    const float* __restrict__ bV,
    bf16* __restrict__ Qb, bf16* __restrict__ Kb, bf16* __restrict__ Vb) {
  __shared__ __align__(16) short As[128 * 64];
  __shared__ __align__(16) short Bs[128 * 64];
  const int flat = blockIdx.x;
  const int xcd = flat & 7, idx = flat >> 3;          // idx 0..63
  const int tileM = (xcd * 2 + (idx >> 5)) * 128;     // token band
  const int tileN = (idx & 31) * 128;                 // feature tile
  const int tid = threadIdx.x, wave = tid >> 6, lane = tid & 63;
  const int wm = (wave >> 1) * 64, wn = (wave & 1) * 64;
  const int mrow = lane & 15, kq = lane >> 4;
  const bool isQK = tileN < 2048;
  f32x4 acc[4][4] = {};

  for (int k0 = 0; k0 < 1024; k0 += 64) {
#pragma unroll
    for (int i = 0; i < 4; i++) {
      int c = (wave * 4 + i) * 64 + lane;          // chunk 0..1023
      int row = c >> 3, j = c & 7, g = j ^ (row & 7);
      const short* ga = (const short*)A + (size_t)(tileM + row) * 1024 + k0 + g * 8;
      const short* gb = (const short*)Bt + (size_t)(tileN + row) * 1024 + k0 + g * 8;
      __builtin_amdgcn_global_load_lds(AS1(ga), AS3(&As[(wave * 4 + i) * 512]), 16, 0, 0);
      __builtin_amdgcn_global_load_lds(AS1(gb), AS3(&Bs[(wave * 4 + i) * 512]), 16, 0, 0);
    }
    __syncthreads();
#pragma unroll
    for (int ks = 0; ks < 2; ks++) {
      bf16x8 af[4], bfr[4];
#pragma unroll
      for (int t = 0; t < 4; t++) {
        int ra = wm + t * 16 + mrow, rb = wn + t * 16 + mrow;
        af[t]  = *(const bf16x8*)&As[ra * 64 + ((ks * 4 + kq) ^ (ra & 7)) * 8];
        bfr[t] = *(const bf16x8*)&Bs[rb * 64 + ((ks * 4 + kq) ^ (rb & 7)) * 8];
      }
      if (isQK) {
#pragma unroll
        for (int fj = 0; fj < 4; fj++)
#pragma unroll
          for (int ti = 0; ti < 4; ti++)
            acc[fj][ti] = __builtin_amdgcn_mfma_f32_16x16x32_bf16(bfr[fj], af[ti], acc[fj][ti], 0, 0, 0);
      } else {
#pragma unroll
        for (int i = 0; i < 4; i++)
#pragma unroll
          for (int j = 0; j < 4; j++)
            acc[i][j] = __builtin_amdgcn_mfma_f32_16x16x32_bf16(af[i], bfr[j], acc[i][j], 0, 0, 0);
      }
    }
    __syncthreads();
  }

  const int col = lane & 15, rq = lane >> 4;
  if (isQK) {
    const int qk = tileN >> 10;
    const float* bias = qk ? bK : bQ;
    const int hA = ((tileN & 1023) + wn) >> 5;
    const int d0 = rq * 4;
    const float4 bA0 = *(const float4*)&bias[hA * 32 + d0];
    const float4 bA1 = *(const float4*)&bias[hA * 32 + 16 + d0];
    const float4 bB0 = *(const float4*)&bias[(hA + 1) * 32 + d0];
    const float4 bB1 = *(const float4*)&bias[(hA + 1) * 32 + 16 + d0];
    float invf[4];
#pragma unroll
    for (int r = 0; r < 4; r++)
      invf[r] = exp2f((d0 + r) * -0.8304820237218406f);  // -log2(10000)/16
    const float osc = qk ? 1.f : INV_SCALE;
#pragma unroll
    for (int ti = 0; ti < 4; ti++) {
      int sg = tileM + wm + ti * 16 + col;
      int s = sg & 1023, bb = sg >> 10;
      float sv[4], cv[4];
#pragma unroll
      for (int r = 0; r < 4; r++) __sincosf((float)s * invf[r], &sv[r], &cv[r]);
#pragma unroll
      for (int p = 0; p < 2; p++) {
        int h = hA + p;
        short4v z0, z1;
#pragma unroll
        for (int r = 0; r < 4; r++) {
          float x0 = acc[2 * p][ti][r]     + (p ? (&bB0.x)[r] : (&bA0.x)[r]);
          float x1 = acc[2 * p + 1][ti][r] + (p ? (&bB1.x)[r] : (&bA1.x)[r]);
          float y0 = (x0 * cv[r] - x1 * sv[r]) * osc;
          float y1 = (x1 * cv[r] + x0 * sv[r]) * osc;
          z0[r] = rnd_bf16(y0); z1[r] = rnd_bf16(y1);
        }
        short* dst = qk
            ? (short*)Kb + ((size_t)(bb * 32 + h) * 1152 + s) * 32
            : (short*)Qb + ((size_t)(bb * 32 + h) * 1024 + s) * 32;
        *(short4v*)(dst + d0) = z0;
        *(short4v*)(dst + 16 + d0) = z1;
      }
    }
  } else {
    const int hv = (tileN - 2048 + wn) >> 6;
#pragma unroll
    for (int i = 0; i < 4; i++)
#pragma unroll
      for (int j = 0; j < 4; j++) {
        int c = j * 16 + col;
        float bias = bV[hv * 64 + c];
        int m0 = tileM + wm + i * 16 + rq * 4;
        int s0 = m0 & 1023, bb = m0 >> 10;
        int chunk = s0 >> 6, w = s0 & 63, u0 = w & 31;
        int p0 = (u0 & 3) | ((u0 & 16) >> 2) | ((u0 & 8) << 1) | ((u0 & 4) << 1);
        int p = (w & 32) | p0;                 // 4-aligned
        int slot = c * 8 + ((p >> 3) ^ (c & 7));
        short4v s4;
#pragma unroll
        for (int r = 0; r < 4; r++) s4[r] = rnd_bf16(acc[i][j][r] + bias);
        *(short4v*)((short*)Vb +
            ((((size_t)(bb * 32 + hv)) * 17 + chunk) * 512 + slot) * 8 + (p & 7)) = s4;
      }
  }
}

// ---- PAIRED-TILE flash attention (unchanged from R9) ----------------------
__global__ __launch_bounds__(256) void attn_mfma(
    const bf16* __restrict__ Qb, const bf16* __restrict__ Kb,
    const bf16* __restrict__ Vb, bf16* __restrict__ Zb) {
  __shared__ __align__(16) short Vs[4][2][4096];
  const int flat = blockIdx.x;                 // 0..511
  const int xcd = flat & 7;
  const int hqb = xcd * 8 + ((flat >> 3) & 7);
  const int xblk = flat >> 6;                  // 0..7
  const int hq = hqb & 31, b = hqb >> 5;
  const int wave = threadIdx.x >> 6, lane = threadIdx.x & 63;
  const int col = lane & 15, quad = lane >> 4;
  const int pairIdx = xblk * 4 + wave;         // 0..31
  const int qwA = pairIdx * 16, qwB = (63 - pairIdx) * 16;

  const short* qbase = (const short*)Qb + ((size_t)(b * 32 + hq)) * 1024 * 32;
  const bf16x8 qfA = *(const bf16x8*)(qbase + (qwA + col) * 32 + quad * 8);
  const bf16x8 qfB = *(const bf16x8*)(qbase + (qwB + col) * 32 + quad * 8);
  const short* kbase = (const short*)Kb + ((size_t)(b * 32 + hq)) * 1152 * 32 + quad * 8;
  const short* vbh = (const short*)Vb + ((size_t)(b * 32 + hq)) * (17 * 4096) + lane * 8;

  const int kendA = qwA + 32;
  const int nchA = (kendA + 63) >> 6;
  const int kendB = (qwB + 32 < 1040) ? qwB + 32 : 1040;
  const int nchB = (kendB + 63) >> 6;          // nchA <= nchB

  f32x4 OA[4] = {}, OB[4] = {};
  float mA = -1e30f, lA = 0.f, mB = -1e30f, lB = 0.f;

  bf16x8 kf[4];
#pragma unroll
  for (int mbk = 0; mbk < 4; mbk++)
    kf[mbk] = *(const bf16x8*)(kbase + (size_t)(mbk * 16 + col) * 32);
  {
    short* vd = &Vs[wave][0][0];
#pragma unroll
    for (int g = 0; g < 8; g++)
      __builtin_amdgcn_global_load_lds(AS1(vbh + g * 512), AS3(vd + g * 512), 16, 0, 0);
  }

  for (int ci = 0; ci < nchB; ci++) {
    const int kc = ci * 64;
    const bool aAct = ci < nchA;
    f32x4 SB[4] = {};
#pragma unroll
    for (int mbk = 0; mbk < 4; mbk++)
      SB[mbk] = __builtin_amdgcn_mfma_f32_16x16x32_bf16(kf[mbk], qfB, SB[mbk], 0, 0, 0);
    f32x4 SA[4] = {};
    if (aAct) {
#pragma unroll
      for (int mbk = 0; mbk < 4; mbk++)
        SA[mbk] = __builtin_amdgcn_mfma_f32_16x16x32_bf16(kf[mbk], qfA, SA[mbk], 0, 0, 0);
    }
    if (kc + 63 > qwB + 16) {
      int qv = qwB + col + 16;
#pragma unroll
      for (int mbk = 0; mbk < 4; mbk++)
#pragma unroll
        for (int r = 0; r < 4; r++)
          if (kc + mbk * 16 + quad * 4 + r > qv) SB[mbk][r] = -1e30f;
    }
    if (aAct && kc + 63 > qwA + 16) {
      int qv = qwA + col + 16;
#pragma unroll
      for (int mbk = 0; mbk < 4; mbk++)
#pragma unroll
        for (int r = 0; r < 4; r++)
          if (kc + mbk * 16 + quad * 4 + r > qv) SA[mbk][r] = -1e30f;
    }
    int4v piB[2], piA[2];
    {
      float c0 = fmaxf(fmaxf(SB[0][0], SB[0][1]), fmaxf(SB[0][2], SB[0][3]));
      float c1 = fmaxf(fmaxf(SB[1][0], SB[1][1]), fmaxf(SB[1][2], SB[1][3]));
      float c2 = fmaxf(fmaxf(SB[2][0], SB[2][1]), fmaxf(SB[2][2], SB[2][3]));
      float c3 = fmaxf(fmaxf(SB[3][0], SB[3][1]), fmaxf(SB[3][2], SB[3][3]));
      float cmax = fmaxf(fmaxf(c0, c1), fmaxf(c2, c3));
      cmax = fmaxf(cmax, __shfl_xor(cmax, 16));
      cmax = fmaxf(cmax, __shfl_xor(cmax, 32));
      float mn = fmaxf(mB, cmax);
      float al = __expf(mB - mn);
      mB = mn;
      float ps = 0.f;
#pragma unroll
      for (int mbk = 0; mbk < 4; mbk++)
#pragma unroll
        for (int r = 0; r < 4; r++) {
          float p = __expf(SB[mbk][r] - mn);
          ps += p;
          SB[mbk][r] = p;
        }
      ps += __shfl_xor(ps, 16);
      ps += __shfl_xor(ps, 32);
      lB = lB * al + ps;
#pragma unroll
      for (int pr = 0; pr < 2; pr++)
#pragma unroll
        for (int d = 0; d < 4; d++)
          piB[pr][d] = pack_bf16_pair(SB[2 * pr + (d >> 1)][(d & 1) * 2 + 1],
                                      SB[2 * pr + (d >> 1)][(d & 1) * 2]);
#pragma unroll
      for (int cb = 0; cb < 4; cb++)
#pragma unroll
        for (int r = 0; r < 4; r++) OB[cb][r] *= al;
    }
    if (aAct) {
      float c0 = fmaxf(fmaxf(SA[0][0], SA[0][1]), fmaxf(SA[0][2], SA[0][3]));
      float c1 = fmaxf(fmaxf(SA[1][0], SA[1][1]), fmaxf(SA[1][2], SA[1][3]));
      float c2 = fmaxf(fmaxf(SA[2][0], SA[2][1]), fmaxf(SA[2][2], SA[2][3]));
      float c3 = fmaxf(fmaxf(SA[3][0], SA[3][1]), fmaxf(SA[3][2], SA[3][3]));
      float cmax = fmaxf(fmaxf(c0, c1), fmaxf(c2, c3));
      cmax = fmaxf(cmax, __shfl_xor(cmax, 16));
      cmax = fmaxf(cmax, __shfl_xor(cmax, 32));
      float mn = fmaxf(mA, cmax);
      float al = __expf(mA - mn);
      mA = mn;
      float ps = 0.f;
#pragma unroll
      for (int mbk = 0; mbk < 4; mbk++)
#pragma unroll
        for (int r = 0; r < 4; r++) {
          float p = __expf(SA[mbk][r] - mn);
          ps += p;
          SA[mbk][r] = p;
        }
      ps += __shfl_xor(ps, 16);
      ps += __shfl_xor(ps, 32);
      lA = lA * al + ps;
#pragma unroll
      for (int pr = 0; pr < 2; pr++)
#pragma unroll
        for (int d = 0; d < 4; d++)
          piA[pr][d] = pack_bf16_pair(SA[2 * pr + (d >> 1)][(d & 1) * 2 + 1],
                                      SA[2 * pr + (d >> 1)][(d & 1) * 2]);
#pragma unroll
      for (int cb = 0; cb < 4; cb++)
#pragma unroll
        for (int r = 0; r < 4; r++) OA[cb][r] *= al;
    }
    asm volatile("s_waitcnt vmcnt(0)" ::: "memory");
    const short* vd = &Vs[wave][ci & 1][0];
    bf16x8 vf[2][4];
#pragma unroll
    for (int ks = 0; ks < 2; ks++)
#pragma unroll
      for (int cb = 0; cb < 4; cb++) {
        int slot = (cb * 16 + col) * 8 + ((ks * 4 + quad) ^ (col & 7));
        vf[ks][cb] = *(const bf16x8*)(vd + slot * 8);
      }
    if (ci + 1 < nchB) {
      const int kn = kc + 64;
#pragma unroll
      for (int mbk = 0; mbk < 4; mbk++)
        kf[mbk] = *(const bf16x8*)(kbase + (size_t)(kn + mbk * 16 + col) * 32);
      const short* vsrc = vbh + (ci + 1) * 4096;
      short* vdn = &Vs[wave][(ci + 1) & 1][0];
#pragma unroll
      for (int g = 0; g < 8; g++)
        __builtin_amdgcn_global_load_lds(AS1(vsrc + g * 512), AS3(vdn + g * 512), 16, 0, 0);
    }
#pragma unroll
    for (int ks = 0; ks < 2; ks++) {
      bf16x8 prB = *(bf16x8*)&piB[ks];
#pragma unroll
      for (int cb = 0; cb < 4; cb++)
        OB[cb] = __builtin_amdgcn_mfma_f32_16x16x32_bf16(vf[ks][cb], prB, OB[cb], 0, 0, 0);
    }
    if (aAct) {
#pragma unroll
      for (int ks = 0; ks < 2; ks++) {
        bf16x8 prA = *(bf16x8*)&piA[ks];
#pragma unroll
        for (int cb = 0; cb < 4; cb++)
          OA[cb] = __builtin_amdgcn_mfma_f32_16x16x32_bf16(vf[ks][cb], prA, OA[cb], 0, 0, 0);
      }
    }
  }
  {
    float inv = 1.f / lA;
    short* zrow = (short*)Zb + ((size_t)(b * 1024 + qwA + col)) * 2048 + hq * 64 + quad * 4;
#pragma unroll
    for (int cb = 0; cb < 4; cb++) {
      short4v s4;
#pragma unroll
      for (int r = 0; r < 4; r++) s4[r] = rnd_bf16(OA[cb][r] * inv);
      *(short4v*)(zrow + cb * 16) = s4;
    }
  }
  {
    float inv = 1.f / lB;
    short* zrow = (short*)Zb + ((size_t)(b * 1024 + qwB + col)) * 2048 + hq * 64 + quad * 4;
#pragma unroll
    for (int cb = 0; cb < 4; cb++) {
      short4v s4;
#pragma unroll
      for (int r = 0; r < 4; r++) s4[r] = rnd_bf16(OB[cb][r] * inv);
      *(short4v*)(zrow + cb * 16) = s4;
    }
  }
}

// ---- GEMM2: 64x64 tile, BK=64, swizzled LDS, 512 blocks -------------------
__global__ __launch_bounds__(256) void gemm2_small(
    const bf16* __restrict__ A, const bf16* __restrict__ Bt, float* __restrict__ C,
    int K, int ldc) {
  __shared__ __align__(16) short As[64 * 64];
  __shared__ __align__(16) short Bs[64 * 64];
  const int tileM = blockIdx.y * 64, tileN = blockIdx.x * 64;
  const int tid = threadIdx.x, wave = tid >> 6, lane = tid & 63;
  const int wm = (wave >> 1) * 32, wn = (wave & 1) * 32;
  const int mrow = lane & 15, kq = lane >> 4;
  f32x4 acc[2][2] = {};

  for (int k0 = 0; k0 < K; k0 += 64) {
#pragma unroll
    for (int i = 0; i < 2; i++) {
      int c = (wave * 2 + i) * 64 + lane;          // chunk 0..511
      int row = c >> 3, j = c & 7, g = j ^ (row & 7);
      const short* ga = (const short*)A + (size_t)(tileM + row) * K + k0 + g * 8;
      const short* gb = (const short*)Bt + (size_t)(tileN + row) * K + k0 + g * 8;
      __builtin_amdgcn_global_load_lds(AS1(ga), AS3(&As[(wave * 2 + i) * 512]), 16, 0, 0);
      __builtin_amdgcn_global_load_lds(AS1(gb), AS3(&Bs[(wave * 2 + i) * 512]), 16, 0, 0);
    }
    __syncthreads();
#pragma unroll
    for (int ks = 0; ks < 2; ks++) {
      bf16x8 af[2], bfr[2];
#pragma unroll
      for (int t = 0; t < 2; t++) {
        int ra = wm + t * 16 + mrow, rb = wn + t * 16 + mrow;
        af[t]  = *(const bf16x8*)&As[ra * 64 + ((ks * 4 + kq) ^ (ra & 7)) * 8];
        bfr[t] = *(const bf16x8*)&Bs[rb * 64 + ((ks * 4 + kq) ^ (rb & 7)) * 8];
      }
#pragma unroll
      for (int i = 0; i < 2; i++)
#pragma unroll
        for (int j = 0; j < 2; j++)
          acc[i][j] = __builtin_amdgcn_mfma_f32_16x16x32_bf16(af[i], bfr[j], acc[i][j], 0, 0, 0);
    }
    __syncthreads();
  }
  const int col = lane & 15, rq = lane >> 4;
#pragma unroll
  for (int i = 0; i < 2; i++)
#pragma unroll
    for (int j = 0; j < 2; j++)
#pragma unroll
      for (int r = 0; r < 4; r++) {
        int mm = tileM + wm + i * 16 + rq * 4 + r;
        int nn = tileN + wn + j * 16 + col;
        C[(size_t)mm * ldc + nn] = acc[i][j][r];
      }
}

// ---------------------------------------------------------------------------
extern "C" void kernel_launch(void* const* d_in, const int* in_sizes, int n_in,
                              void* d_out, int out_size, void* d_ws, size_t ws_size,
                              hipStream_t stream) {
  const float* resid = (const float*)d_in[0];
  const float* WQ = (const float*)d_in[1];
  const float* WK = (const float*)d_in[2];
  const float* WV = (const float*)d_in[3];
  const float* WO = (const float*)d_in[4];
  const float* bQ = (const float*)d_in[5];
  const float* bK = (const float*)d_in[6];
  const float* bV = (const float*)d_in[7];
  const float* vk = (const float*)d_in[8];
  const float* vv = (const float*)d_in[9];
  float* out = (float*)d_out;

  // workspace layout, no aliasing (~41.5 MB):
  char* ws = (char*)d_ws;
  bf16* A_bf = (bf16*)(ws);                 // 4 MB   [2048][1024]
  bf16* Wt   = (bf16*)(ws + 4194304);       // 8 MB   [4096][1024]
  bf16* Wot  = (bf16*)(ws + 12582912);      // 4 MB   [1024][2048]
  bf16* Qb   = (bf16*)(ws + 16777216);      // 4 MB   [(b,h)][1024][32] scaled
  bf16* Kb   = (bf16*)(ws + 20971520);      // 4.5 MB [(b,h)][1152][32]
  bf16* Vb   = (bf16*)(ws + 25690112);      // 8.5 MB [(b,h)][17][512 slots][8]
  bf16* Zb   = (bf16*)(ws + 35127296);      // 8 MB   [2048][2048]

  prep<<<8704, 256, 0, stream>>>(resid, WV, WQ, WK, WO, vk, vv, A_bf, Wt, Wot, Kb, Vb);
  gemm1_fused<<<512, 256, 0, stream>>>(A_bf, Wt, bQ, bK, bV, Qb, Kb, Vb);
  attn_mfma<<<512, 256, 0, stream>>>(Qb, Kb, Vb, Zb);
  gemm2_small<<<dim3(16, 32), 256, 0, stream>>>(Zb, Wot, out, 2048, 1024);
}